// Round 5
// baseline (241.739 us; speedup 1.0000x reference)
//
#include <hip/hip_runtime.h>

// ---------------- types ----------------
typedef __bf16 bf16x8 __attribute__((ext_vector_type(8)));
typedef float  f32x4  __attribute__((ext_vector_type(4)));
typedef unsigned short ushort8 __attribute__((ext_vector_type(8)));

#define B_ROWS 8192
#define OUT_D  512
#define O2C_D  256
#define TOT_D  768
#define MIN_D  768
#define RNN_D  1024

__device__ __forceinline__ unsigned short f2bf(float f) {
    unsigned int u = __builtin_bit_cast(unsigned int, f);
    u = (u + 0x7fff + ((u >> 16) & 1)) >> 16;   // RNE
    return (unsigned short)u;
}

__device__ __forceinline__ void load_lds16(const void* g, void* l) {
    __builtin_amdgcn_global_load_lds(
        (const __attribute__((address_space(1))) unsigned int*)g,
        (__attribute__((address_space(3))) unsigned int*)l, 16, 0, 0);
}

// ---------------- fused prep kernel ----------------
// blockIdx segments: [0,128) reduce_sq partials; [128,1984) weight cvt; [1984,10176) act cvt
__launch_bounds__(256)
__global__ void prep_all(const float* __restrict__ Wread, float* __restrict__ partials,
                         const float* __restrict__ Wpre, const float* __restrict__ Wx,
                         const float* __restrict__ Wh,  const float* __restrict__ Wpost,
                         unsigned short* __restrict__ WpreT, unsigned short* __restrict__ WxhT,
                         unsigned short* __restrict__ WpostT, unsigned short* __restrict__ WreadT,
                         const float* __restrict__ center, const float* __restrict__ inputs,
                         const float* __restrict__ mstate,
                         unsigned short* __restrict__ csB, unsigned short* __restrict__ miB,
                         unsigned short* __restrict__ rnB) {
    const int bid = blockIdx.x;
    const int tid = threadIdx.x;
    if (bid < 128) {
        __shared__ float red[4];
        const float* p = Wread + bid * 1024 + tid * 4;
        f32x4 v = *(const f32x4*)p;
        float s = v[0]*v[0] + v[1]*v[1] + v[2]*v[2] + v[3]*v[3];
        #pragma unroll
        for (int off = 32; off > 0; off >>= 1) s += __shfl_down(s, off, 64);
        if ((tid & 63) == 0) red[tid >> 6] = s;
        __syncthreads();
        if (tid == 0) partials[bid] = red[0] + red[1] + red[2] + red[3];
        return;
    }
    if (bid < 1984) {
        int g = (bid - 128) * 256 + tid;
        const float* W; unsigned short* out; int N, ostride;
        if (g < 98304)        { W = Wpre;  out = WpreT;        N = 1024; ostride = 768;  }
        else if (g < 229376)  { g -= 98304;  W = Wx;    out = WxhT;        N = 1024; ostride = 2048; }
        else if (g < 360448)  { g -= 229376; W = Wh;    out = WxhT + 1024; N = 1024; ostride = 2048; }
        else if (g < 458752)  { g -= 360448; W = Wpost; out = WpostT;      N = 768;  ostride = 1024; }
        else                  { g -= 458752; W = Wread; out = WreadT;      N = 256;  ostride = 512;  }
        int n  = g % N;
        int kg = g / N;
        ushort8 o;
        #pragma unroll
        for (int j = 0; j < 8; ++j)
            o[j] = f2bf(W[(long)(kg * 8 + j) * N + n]);
        *(ushort8*)(out + (long)n * ostride + kg * 8) = o;
        return;
    }
    long g = (long)(bid - 1984) * 256 + tid;
    const float* src; unsigned short* dst; int logc, ostride;
    if (g < 524288)       { src = center; dst = csB;        logc = 9;  ostride = 512;  }
    else if (g < 1048576) { g -= 524288;  src = inputs; dst = miB;        logc = 9;  ostride = 768;  }
    else                  { g -= 1048576; src = mstate; dst = rnB + 1024; logc = 10; ostride = 2048; }
    long e = g * 8;
    long row = e >> logc;
    int  col = (int)(e & ((1 << logc) - 1));
    f32x4 v0 = *(const f32x4*)(src + e);
    f32x4 v1 = *(const f32x4*)(src + e + 4);
    ushort8 o;
    o[0] = f2bf(v0[0]); o[1] = f2bf(v0[1]); o[2] = f2bf(v0[2]); o[3] = f2bf(v0[3]);
    o[4] = f2bf(v1[0]); o[5] = f2bf(v1[1]); o[6] = f2bf(v1[2]); o[7] = f2bf(v1[3]);
    *(ushort8*)(dst + row * (long)ostride + col) = o;
}

// ---------------- GEMM (single-buffer, round-0 proven) ----------------
// BM=128, BNT in {64,128}, BK=64. 4 waves: wm=wave&1, wn=wave>>1.
// Conflict-free swizzle: chunk (row,kg) at slot row*8+(kg^(row&7)); read (kh*4+lr)^(lc&7).
// MODE 0: *clipscale -> bf16 | MODE 1: bias+relu -> bf16 | MODE 3: bias+relu -> fp32 split
template<int MODE, int BNT>
__launch_bounds__(256, 4)
__global__ void gemm_bt(const unsigned short* __restrict__ A,
                        const unsigned short* __restrict__ Bt,
                        int K, const float* __restrict__ bias,
                        unsigned short* __restrict__ outB, int ldob,
                        float* __restrict__ outF, int ldof) {
    constexpr int U   = BNT / 32;
    constexpr int BJ  = BNT / 32;
    __shared__ alignas(16) unsigned short smem[128 * 64 + BNT * 64];
    unsigned short* sA = smem;
    unsigned short* sB = smem + 128 * 64;

    const int tid  = threadIdx.x;
    const int wave = tid >> 6;
    const int lane = tid & 63;
    const int bm = blockIdx.x, bn = blockIdx.y;
    const int wm = wave & 1, wn = wave >> 1;
    const int lr = lane >> 4;
    const int lc = lane & 15;
    const int sw = lc & 7;

    f32x4 acc[4][U] = {};

    long aoff[4], boff[BJ];
    #pragma unroll
    for (int j = 0; j < 4; ++j) {
        const int c   = tid + j * 256;
        const int row = c >> 3;
        const int kg  = (c & 7) ^ (row & 7);
        aoff[j] = (long)(bm * 128 + row) * K + kg * 8;
    }
    #pragma unroll
    for (int j = 0; j < BJ; ++j) {
        const int c   = tid + j * 256;
        const int row = c >> 3;
        const int kg  = (c & 7) ^ (row & 7);
        boff[j] = (long)(bn * BNT + row) * K + kg * 8;
    }

    for (int k0 = 0; k0 < K; k0 += 64) {
        #pragma unroll
        for (int j = 0; j < 4; ++j)
            load_lds16(A + aoff[j] + k0, (char*)sA + j * 4096 + wave * 1024);
        #pragma unroll
        for (int j = 0; j < BJ; ++j)
            load_lds16(Bt + boff[j] + k0, (char*)sB + j * 4096 + wave * 1024);
        __syncthreads();

        #pragma unroll
        for (int kh = 0; kh < 2; ++kh) {
            const int ch = (kh * 4 + lr) ^ sw;
            bf16x8 af[4], bfr[U];
            #pragma unroll
            for (int t = 0; t < 4; ++t)
                af[t] = *(const bf16x8*)(sA + (wm * 64 + t * 16 + lc) * 64 + ch * 8);
            #pragma unroll
            for (int u = 0; u < U; ++u)
                bfr[u] = *(const bf16x8*)(sB + (wn * (BNT / 2) + u * 16 + lc) * 64 + ch * 8);
            #pragma unroll
            for (int i = 0; i < 4; ++i)
                #pragma unroll
                for (int u = 0; u < U; ++u)
                    acc[i][u] = __builtin_amdgcn_mfma_f32_16x16x32_bf16(af[i], bfr[u], acc[i][u], 0, 0, 0);
        }
        __syncthreads();
    }

    float sc = 1.f;
    if constexpr (MODE == 0) {
        float s = 0.f;
        for (int i = 0; i < 128; ++i) s += bias[i];
        sc = 1.f / fmaxf(sqrtf(s), 1.f);
    }
    #pragma unroll
    for (int u = 0; u < U; ++u) {
        float bv = 0.f;
        if constexpr (MODE != 0) bv = bias[bn * BNT + wn * (BNT / 2) + u * 16 + lc];
        #pragma unroll
        for (int tm = 0; tm < 4; ++tm)
            #pragma unroll
            for (int r = 0; r < 4; ++r) {
                float v = acc[tm][u][r];
                if constexpr (MODE == 0) v *= sc;
                else v += bv;
                if constexpr (MODE == 1 || MODE == 3) v = fmaxf(v, 0.f);
                acc[tm][u][r] = v;
            }
    }

    const int ctcol = wn * (BNT / 2);

    if constexpr (MODE <= 2) {
        unsigned short* Cb = smem;
        #pragma unroll
        for (int u = 0; u < U; ++u)
            #pragma unroll
            for (int tm = 0; tm < 4; ++tm)
                #pragma unroll
                for (int r = 0; r < 4; ++r)
                    Cb[(wm * 64 + tm * 16 + lr * 4 + r) * BNT + ctcol + u * 16 + lc] =
                        f2bf(acc[tm][u][r]);
        __syncthreads();
        constexpr int RC = BNT / 8;
        constexpr int CPT = 128 * RC / 256;
        #pragma unroll
        for (int t = 0; t < CPT; ++t) {
            const int chunk = t * 256 + tid;
            const int row = chunk / RC;
            const int c8  = chunk % RC;
            ushort8 val = *(ushort8*)(Cb + row * BNT + c8 * 8);
            *(ushort8*)(outB + (long)(bm * 128 + row) * ldob + bn * BNT + c8 * 8) = val;
        }
    }

    if constexpr (MODE == 3) {
        float* Cf = (float*)smem;
        #pragma unroll
        for (int h = 0; h < 2; ++h) {
            __syncthreads();
            if (wm == h) {
                #pragma unroll
                for (int u = 0; u < U; ++u)
                    #pragma unroll
                    for (int tm = 0; tm < 4; ++tm)
                        #pragma unroll
                        for (int r = 0; r < 4; ++r)
                            Cf[(tm * 16 + lr * 4 + r) * BNT + ctcol + u * 16 + lc] =
                                acc[tm][u][r];
            }
            __syncthreads();
            constexpr int RCF = BNT / 4;
            constexpr int CPTF = 64 * RCF / 256;
            #pragma unroll
            for (int t = 0; t < CPTF; ++t) {
                const int chunk = t * 256 + tid;
                const int row = chunk / RCF;
                const int c4  = chunk % RCF;
                f32x4 val = *(f32x4*)(Cf + row * BNT + c4 * 4);
                const long grow = bm * 128 + h * 64 + row;
                if (bn * BNT < OUT_D)
                    *(f32x4*)(outF + grow * OUT_D + bn * BNT + c4 * 4) = val;
                else
                    *(f32x4*)(outF + (long)B_ROWS * OUT_D + grow * O2C_D
                              + (bn * BNT - OUT_D) + c4 * 4) = val;
            }
        }
    }
}

// ---------------- L3 deep-pipelined GEMM: 256x128, tri-buffer, counted waits ----------------
// 8 waves (4M x 2N), per-wave 64x64. BK=64, 2 phases/K-tile. Requires K >= 128.
// R4 lesson: phase-serial {ds_read -> lgkmcnt(0) -> MFMA} alternates LDS and matrix
// pipes (23% MfmaUtil). Fix: fragment ping-pong F0/F1 with COUNTED lgkmcnt(8) —
// issue next phase's 8 ds_reads, wait only the older 8, MFMA the older set. LDS
// reads fly under MFMA (AITER 1:1 interleave, T4-on-DS).
// Staging: all 6 loads of tile t+2 issued in ph0; vmcnt(6) after ph0 MFMA drains
// tile t+1 -> barrier makes t+1 visible -> ph1 may read t+1's ph0 frags.
// Hazards: lgkm(8) drains exactly the older frag set each phase; last reads of
// buf[t%3] drain at t-ph1 wait, next write to it issues t+1-ph0 after a barrier;
// F0' reads target buf[(t+1)%3] != staged buf[(t+2)%3]. vmcnt(0) tail at t=nt-2.
// Grid: linear 256; xcd=i&7, bm=xcd+8*((i>>3)&3), bn=i>>5 -> the 8 blocks sharing
// an A-tile (same bm) land on ONE XCD (dispatch = i%8) -> A fetched from HBM once
// (R4: bn-fast put same-bn on one XCD -> each XCD streamed ALL of A, FETCH 133MB).
// Output: bias+tanh -> bf16 hB + fp32 h.
__launch_bounds__(512, 1)
__global__ void gemm256(const unsigned short* __restrict__ A,
                        const unsigned short* __restrict__ Bt,
                        int K, const float* __restrict__ bias,
                        unsigned short* __restrict__ outB,
                        float* __restrict__ outF) {
    constexpr int ABUF = 256 * 64;           // ushorts (32 KB)
    constexpr int BBUF = 128 * 64;           // ushorts (16 KB)
    constexpr int BUFE = ABUF + BBUF;        // 48 KB
    __shared__ alignas(16) unsigned short smem[3 * BUFE];   // 144 KB

    const int tid  = threadIdx.x;
    const int wave = tid >> 6;
    const int lane = tid & 63;
    const int i  = blockIdx.x;
    const int bm = (i & 7) + 8 * ((i >> 3) & 3);   // same-bm octet -> same XCD
    const int bn = i >> 5;
    const int wm = wave >> 1, wn = wave & 1;
    const int lr = lane >> 4;
    const int lc = lane & 15;
    const int sw = lc & 7;
    const int nt = K >> 6;

    f32x4 acc[4][4] = {};

    long aoff[4], boff[2];
    #pragma unroll
    for (int j = 0; j < 4; ++j) {
        const int c   = tid + j * 512;
        const int row = c >> 3;
        const int kg  = (c & 7) ^ (row & 7);
        aoff[j] = (long)(bm * 256 + row) * K + kg * 8;
    }
    #pragma unroll
    for (int j = 0; j < 2; ++j) {
        const int c   = tid + j * 512;
        const int row = c >> 3;
        const int kg  = (c & 7) ^ (row & 7);
        boff[j] = (long)(bn * 128 + row) * K + kg * 8;
    }

    auto stage6 = [&](int buf, int k0) {     // all 6 loads of one K-tile
        char* base = (char*)(smem + buf * BUFE);
        #pragma unroll
        for (int j = 0; j < 4; ++j)
            load_lds16(A + aoff[j] + k0, base + j * 8192 + wave * 1024);
        char* bbase = base + ABUF * 2;
        #pragma unroll
        for (int j = 0; j < 2; ++j)
            load_lds16(Bt + boff[j] + k0, bbase + j * 8192 + wave * 1024);
    };
    auto dsA = [&](int buf, int kh, bf16x8* af) {
        const unsigned short* sA = smem + buf * BUFE;
        const int ch = (kh * 4 + lr) ^ sw;
        #pragma unroll
        for (int m = 0; m < 4; ++m)
            af[m] = *(const bf16x8*)(sA + (wm * 64 + m * 16 + lc) * 64 + ch * 8);
    };
    auto dsB = [&](int buf, int kh, bf16x8* bf) {
        const unsigned short* sB = smem + buf * BUFE + ABUF;
        const int ch = (kh * 4 + lr) ^ sw;
        #pragma unroll
        for (int n = 0; n < 4; ++n)
            bf[n] = *(const bf16x8*)(sB + (wn * 64 + n * 16 + lc) * 64 + ch * 8);
    };

    bf16x8 af0[4], bf0[4], af1[4], bf1[4];

    auto mfma16 = [&](const bf16x8* af, const bf16x8* bf) {
        __builtin_amdgcn_s_setprio(1);
        #pragma unroll
        for (int m = 0; m < 4; ++m)
            #pragma unroll
            for (int n = 0; n < 4; ++n)
                acc[m][n] = __builtin_amdgcn_mfma_f32_16x16x32_bf16(af[m], bf[n], acc[m][n], 0, 0, 0);
        __builtin_amdgcn_s_setprio(0);
    };

    // prologue (nt >= 2): stage tiles 0,1; make tile0 visible; preload F0
    stage6(0, 0);
    stage6(1, 64);
    asm volatile("s_waitcnt vmcnt(6)" ::: "memory");   // tile 0 landed
    __builtin_amdgcn_s_barrier();
    dsA(0, 0, af0); dsB(0, 0, bf0);                     // F0 = frags(t0, ph0)

    int cur = 0, nxt = 1;
    for (int t = 0; t < nt; ++t) {
        const bool st = (t + 2) < nt;
        const int  nbuf = (cur >= 1) ? cur - 1 : 2;     // (t+2)%3

        // ---- phase 0: MFMA F0(t,ph0); prefetch F1(t,ph1); stage t+2 ----
        if (st) stage6(nbuf, (t + 2) << 6);
        dsA(cur, 1, af1); dsB(cur, 1, bf1);
        asm volatile("s_waitcnt lgkmcnt(8)" ::: "memory");   // drain F0, F1 in flight
        __builtin_amdgcn_sched_barrier(0);
        mfma16(af0, bf0);
        if (t + 1 < nt) {
            if (st) asm volatile("s_waitcnt vmcnt(6)" ::: "memory");  // tile t+1 landed
            else    asm volatile("s_waitcnt vmcnt(0)" ::: "memory");  // tail drain
        }
        __builtin_amdgcn_s_barrier();                   // t+1 visible to all waves

        // ---- phase 1: MFMA F1(t,ph1); prefetch F0(t+1,ph0) ----
        if (t + 1 < nt) {
            dsA(nxt, 0, af0); dsB(nxt, 0, bf0);
            asm volatile("s_waitcnt lgkmcnt(8)" ::: "memory");  // drain F1
        } else {
            asm volatile("s_waitcnt lgkmcnt(0)" ::: "memory");
        }
        __builtin_amdgcn_sched_barrier(0);
        mfma16(af1, bf1);
        __builtin_amdgcn_s_barrier();                   // buf[(t+3)%3] write-safe

        cur = nxt;
        nxt = (nxt == 2) ? 0 : nxt + 1;
    }

    // ---- epilogue: bias + tanh, then staged coalesced writes ----
    #pragma unroll
    for (int n = 0; n < 4; ++n) {
        const float bv = bias[bn * 128 + wn * 64 + n * 16 + lc];
        #pragma unroll
        for (int m = 0; m < 4; ++m)
            #pragma unroll
            for (int r = 0; r < 4; ++r)
                acc[m][n][r] = tanhf(acc[m][n][r] + bv);
    }

    // bf16 tile (256x128 = 64 KB)
    unsigned short* Cb = smem;
    __syncthreads();
    #pragma unroll
    for (int m = 0; m < 4; ++m)
        #pragma unroll
        for (int n = 0; n < 4; ++n)
            #pragma unroll
            for (int r = 0; r < 4; ++r)
                Cb[(wm * 64 + m * 16 + lr * 4 + r) * 128 + wn * 64 + n * 16 + lc] =
                    f2bf(acc[m][n][r]);
    __syncthreads();
    #pragma unroll
    for (int tch = 0; tch < 8; ++tch) {
        const int chunk = tch * 512 + tid;
        const int row = chunk >> 4;       // 16 chunks of 16B per row
        const int c8  = chunk & 15;
        ushort8 v = *(ushort8*)(Cb + row * 128 + c8 * 8);
        *(ushort8*)(outB + (long)(bm * 256 + row) * RNN_D + bn * 128 + c8 * 8) = v;
    }
    __syncthreads();

    // fp32 tile (256x128 = 128 KB)
    float* Cf = (float*)smem;
    #pragma unroll
    for (int m = 0; m < 4; ++m)
        #pragma unroll
        for (int n = 0; n < 4; ++n)
            #pragma unroll
            for (int r = 0; r < 4; ++r)
                Cf[(wm * 64 + m * 16 + lr * 4 + r) * 128 + wn * 64 + n * 16 + lc] =
                    acc[m][n][r];
    __syncthreads();
    #pragma unroll
    for (int tch = 0; tch < 16; ++tch) {
        const int chunk = tch * 512 + tid;
        const int row = chunk >> 5;       // 32 f32x4 per row
        const int c4  = chunk & 31;
        f32x4 v = *(f32x4*)(Cf + row * 128 + c4 * 4);
        *(f32x4*)(outF + (long)(bm * 256 + row) * RNN_D + bn * 128 + c4 * 4) = v;
    }
}

// ---------------- launch ----------------
extern "C" void kernel_launch(void* const* d_in, const int* in_sizes, int n_in,
                              void* d_out, int out_size, void* d_ws, size_t ws_size,
                              hipStream_t stream) {
    const float* inputs = (const float*)d_in[0];
    const float* center = (const float*)d_in[1];
    const float* mstate = (const float*)d_in[2];
    const float* W_read = (const float*)d_in[3];
    const float* W_pre  = (const float*)d_in[4];
    const float* b_pre  = (const float*)d_in[5];
    const float* Wx     = (const float*)d_in[6];
    const float* Wh     = (const float*)d_in[7];
    const float* b_rnn  = (const float*)d_in[8];
    const float* W_post = (const float*)d_in[9];
    const float* b_post = (const float*)d_in[10];
    float* out = (float*)d_out;

    char* ws = (char*)d_ws;
    float* partials = (float*)ws;                                  // 128 floats
    unsigned short* WreadT = (unsigned short*)(ws + 1024);         // 256 x 512
    unsigned short* WpreT  = WreadT + 256 * 512;                   // 1024 x 768
    unsigned short* WxhT   = WpreT  + 1024 * 768;                  // 1024 x 2048
    unsigned short* WpostT = WxhT   + (long)1024 * 2048;           // 768 x 1024
    unsigned short* csB    = WpostT + 768 * 1024;                  // 8192 x 512
    unsigned short* miB    = csB + (long)B_ROWS * 512;             // 8192 x 768  [inputs | ctx]
    unsigned short* rnB    = miB + (long)B_ROWS * MIN_D;           // 8192 x 2048 [rnn_in | ms]
    unsigned short* hB     = rnB + (long)B_ROWS * 2048;            // 8192 x 1024

    prep_all<<<10176, 256, 0, stream>>>(W_read, partials,
                                        W_pre, Wx, Wh, W_post,
                                        WpreT, WxhT, WpostT, WreadT,
                                        center, inputs, mstate, csB, miB, rnB);

    // L1: context = (cs @ W_read) * clipscale -> miB cols [512..767]
    gemm_bt<0, 64><<<dim3(64, 4), 256, 0, stream>>>(csB, WreadT, 512, partials,
                                                    miB + 512, MIN_D, nullptr, 0);
    // L2: rnn_in = relu(mi @ W_pre + b_pre) -> rnB cols [0..1023]
    gemm_bt<1, 128><<<dim3(64, 8), 256, 0, stream>>>(miB, WpreT, 768, b_pre,
                                                     rnB, 2048, nullptr, 0);
    // L3: h = tanh([rnn_in|ms] @ [Wx;Wh] + b_rnn) -> hB (bf16) + d_out region 2 (fp32)
    gemm256<<<256, 512, 0, stream>>>(rnB, WxhT, 2048, b_rnn,
                                     hB, out + (long)B_ROWS * TOT_D);
    // L4: module_output = relu(h @ W_post + b_post) -> fp32 d_out regions 0/1
    gemm_bt<3, 64><<<dim3(64, 12), 256, 0, stream>>>(hB, WpostT, 1024, b_post,
                                                     nullptr, 0, out, 0);
}

// Round 6
// 240.568 us; speedup vs baseline: 1.0049x; 1.0049x over previous
//
#include <hip/hip_runtime.h>

// ---------------- types ----------------
typedef __bf16 bf16x8 __attribute__((ext_vector_type(8)));
typedef float  f32x4  __attribute__((ext_vector_type(4)));
typedef unsigned short ushort8 __attribute__((ext_vector_type(8)));

#define B_ROWS 8192
#define OUT_D  512
#define O2C_D  256
#define TOT_D  768
#define MIN_D  768
#define RNN_D  1024

__device__ __forceinline__ unsigned short f2bf(float f) {
    unsigned int u = __builtin_bit_cast(unsigned int, f);
    u = (u + 0x7fff + ((u >> 16) & 1)) >> 16;   // RNE
    return (unsigned short)u;
}

__device__ __forceinline__ void load_lds16(const void* g, void* l) {
    __builtin_amdgcn_global_load_lds(
        (const __attribute__((address_space(1))) unsigned int*)g,
        (__attribute__((address_space(3))) unsigned int*)l, 16, 0, 0);
}

// ---------------- fused prep kernel ----------------
// blockIdx segments: [0,128) reduce_sq partials; [128,1984) weight cvt; [1984,10176) act cvt
__launch_bounds__(256)
__global__ void prep_all(const float* __restrict__ Wread, float* __restrict__ partials,
                         const float* __restrict__ Wpre, const float* __restrict__ Wx,
                         const float* __restrict__ Wh,  const float* __restrict__ Wpost,
                         unsigned short* __restrict__ WpreT, unsigned short* __restrict__ WxhT,
                         unsigned short* __restrict__ WpostT, unsigned short* __restrict__ WreadT,
                         const float* __restrict__ center, const float* __restrict__ inputs,
                         const float* __restrict__ mstate,
                         unsigned short* __restrict__ csB, unsigned short* __restrict__ miB,
                         unsigned short* __restrict__ rnB) {
    const int bid = blockIdx.x;
    const int tid = threadIdx.x;
    if (bid < 128) {
        __shared__ float red[4];
        const float* p = Wread + bid * 1024 + tid * 4;
        f32x4 v = *(const f32x4*)p;
        float s = v[0]*v[0] + v[1]*v[1] + v[2]*v[2] + v[3]*v[3];
        #pragma unroll
        for (int off = 32; off > 0; off >>= 1) s += __shfl_down(s, off, 64);
        if ((tid & 63) == 0) red[tid >> 6] = s;
        __syncthreads();
        if (tid == 0) partials[bid] = red[0] + red[1] + red[2] + red[3];
        return;
    }
    if (bid < 1984) {
        int g = (bid - 128) * 256 + tid;
        const float* W; unsigned short* out; int N, ostride;
        if (g < 98304)        { W = Wpre;  out = WpreT;        N = 1024; ostride = 768;  }
        else if (g < 229376)  { g -= 98304;  W = Wx;    out = WxhT;        N = 1024; ostride = 2048; }
        else if (g < 360448)  { g -= 229376; W = Wh;    out = WxhT + 1024; N = 1024; ostride = 2048; }
        else if (g < 458752)  { g -= 360448; W = Wpost; out = WpostT;      N = 768;  ostride = 1024; }
        else                  { g -= 458752; W = Wread; out = WreadT;      N = 256;  ostride = 512;  }
        int n  = g % N;
        int kg = g / N;
        ushort8 o;
        #pragma unroll
        for (int j = 0; j < 8; ++j)
            o[j] = f2bf(W[(long)(kg * 8 + j) * N + n]);
        *(ushort8*)(out + (long)n * ostride + kg * 8) = o;
        return;
    }
    long g = (long)(bid - 1984) * 256 + tid;
    const float* src; unsigned short* dst; int logc, ostride;
    if (g < 524288)       { src = center; dst = csB;        logc = 9;  ostride = 512;  }
    else if (g < 1048576) { g -= 524288;  src = inputs; dst = miB;        logc = 9;  ostride = 768;  }
    else                  { g -= 1048576; src = mstate; dst = rnB + 1024; logc = 10; ostride = 2048; }
    long e = g * 8;
    long row = e >> logc;
    int  col = (int)(e & ((1 << logc) - 1));
    f32x4 v0 = *(const f32x4*)(src + e);
    f32x4 v1 = *(const f32x4*)(src + e + 4);
    ushort8 o;
    o[0] = f2bf(v0[0]); o[1] = f2bf(v0[1]); o[2] = f2bf(v0[2]); o[3] = f2bf(v0[3]);
    o[4] = f2bf(v1[0]); o[5] = f2bf(v1[1]); o[6] = f2bf(v1[2]); o[7] = f2bf(v1[3]);
    *(ushort8*)(dst + row * (long)ostride + col) = o;
}

// ---------------- GEMM (single-buffer, round-0 proven) ----------------
// BM=128, BNT in {64,128}, BK=64. 4 waves: wm=wave&1, wn=wave>>1.
// Conflict-free swizzle: chunk (row,kg) at slot row*8+(kg^(row&7)); read (kh*4+lr)^(lc&7).
// Regime note (R1/R2/R6): this structure needs >=3-4 blocks/CU; BNT=64 @ 24KB LDS.
// BNT=128 at 2 blocks/CU measured 347 TF vs 537 TF at BNT=64 4/CU -> use BNT=64.
// MODE 0: *clipscale -> bf16 | MODE 1: bias+relu -> bf16 | MODE 3: bias+relu -> fp32 split
template<int MODE, int BNT>
__launch_bounds__(256, 4)
__global__ void gemm_bt(const unsigned short* __restrict__ A,
                        const unsigned short* __restrict__ Bt,
                        int K, const float* __restrict__ bias,
                        unsigned short* __restrict__ outB, int ldob,
                        float* __restrict__ outF, int ldof) {
    constexpr int U   = BNT / 32;
    constexpr int BJ  = BNT / 32;
    __shared__ alignas(16) unsigned short smem[128 * 64 + BNT * 64];
    unsigned short* sA = smem;
    unsigned short* sB = smem + 128 * 64;

    const int tid  = threadIdx.x;
    const int wave = tid >> 6;
    const int lane = tid & 63;
    const int bm = blockIdx.x, bn = blockIdx.y;
    const int wm = wave & 1, wn = wave >> 1;
    const int lr = lane >> 4;
    const int lc = lane & 15;
    const int sw = lc & 7;

    f32x4 acc[4][U] = {};

    long aoff[4], boff[BJ];
    #pragma unroll
    for (int j = 0; j < 4; ++j) {
        const int c   = tid + j * 256;
        const int row = c >> 3;
        const int kg  = (c & 7) ^ (row & 7);
        aoff[j] = (long)(bm * 128 + row) * K + kg * 8;
    }
    #pragma unroll
    for (int j = 0; j < BJ; ++j) {
        const int c   = tid + j * 256;
        const int row = c >> 3;
        const int kg  = (c & 7) ^ (row & 7);
        boff[j] = (long)(bn * BNT + row) * K + kg * 8;
    }

    for (int k0 = 0; k0 < K; k0 += 64) {
        #pragma unroll
        for (int j = 0; j < 4; ++j)
            load_lds16(A + aoff[j] + k0, (char*)sA + j * 4096 + wave * 1024);
        #pragma unroll
        for (int j = 0; j < BJ; ++j)
            load_lds16(Bt + boff[j] + k0, (char*)sB + j * 4096 + wave * 1024);
        __syncthreads();

        #pragma unroll
        for (int kh = 0; kh < 2; ++kh) {
            const int ch = (kh * 4 + lr) ^ sw;
            bf16x8 af[4], bfr[U];
            #pragma unroll
            for (int t = 0; t < 4; ++t)
                af[t] = *(const bf16x8*)(sA + (wm * 64 + t * 16 + lc) * 64 + ch * 8);
            #pragma unroll
            for (int u = 0; u < U; ++u)
                bfr[u] = *(const bf16x8*)(sB + (wn * (BNT / 2) + u * 16 + lc) * 64 + ch * 8);
            #pragma unroll
            for (int i = 0; i < 4; ++i)
                #pragma unroll
                for (int u = 0; u < U; ++u)
                    acc[i][u] = __builtin_amdgcn_mfma_f32_16x16x32_bf16(af[i], bfr[u], acc[i][u], 0, 0, 0);
        }
        __syncthreads();
    }

    float sc = 1.f;
    if constexpr (MODE == 0) {
        float s = 0.f;
        for (int i = 0; i < 128; ++i) s += bias[i];
        sc = 1.f / fmaxf(sqrtf(s), 1.f);
    }
    #pragma unroll
    for (int u = 0; u < U; ++u) {
        float bv = 0.f;
        if constexpr (MODE != 0) bv = bias[bn * BNT + wn * (BNT / 2) + u * 16 + lc];
        #pragma unroll
        for (int tm = 0; tm < 4; ++tm)
            #pragma unroll
            for (int r = 0; r < 4; ++r) {
                float v = acc[tm][u][r];
                if constexpr (MODE == 0) v *= sc;
                else v += bv;
                if constexpr (MODE == 1 || MODE == 3) v = fmaxf(v, 0.f);
                acc[tm][u][r] = v;
            }
    }

    const int ctcol = wn * (BNT / 2);

    if constexpr (MODE <= 2) {
        unsigned short* Cb = smem;
        #pragma unroll
        for (int u = 0; u < U; ++u)
            #pragma unroll
            for (int tm = 0; tm < 4; ++tm)
                #pragma unroll
                for (int r = 0; r < 4; ++r)
                    Cb[(wm * 64 + tm * 16 + lr * 4 + r) * BNT + ctcol + u * 16 + lc] =
                        f2bf(acc[tm][u][r]);
        __syncthreads();
        constexpr int RC = BNT / 8;
        constexpr int CPT = 128 * RC / 256;
        #pragma unroll
        for (int t = 0; t < CPT; ++t) {
            const int chunk = t * 256 + tid;
            const int row = chunk / RC;
            const int c8  = chunk % RC;
            ushort8 val = *(ushort8*)(Cb + row * BNT + c8 * 8);
            *(ushort8*)(outB + (long)(bm * 128 + row) * ldob + bn * BNT + c8 * 8) = val;
        }
    }

    if constexpr (MODE == 3) {
        float* Cf = (float*)smem;
        #pragma unroll
        for (int h = 0; h < 2; ++h) {
            __syncthreads();
            if (wm == h) {
                #pragma unroll
                for (int u = 0; u < U; ++u)
                    #pragma unroll
                    for (int tm = 0; tm < 4; ++tm)
                        #pragma unroll
                        for (int r = 0; r < 4; ++r)
                            Cf[(tm * 16 + lr * 4 + r) * BNT + ctcol + u * 16 + lc] =
                                acc[tm][u][r];
            }
            __syncthreads();
            constexpr int RCF = BNT / 4;
            constexpr int CPTF = 64 * RCF / 256;
            #pragma unroll
            for (int t = 0; t < CPTF; ++t) {
                const int chunk = t * 256 + tid;
                const int row = chunk / RCF;
                const int c4  = chunk % RCF;
                f32x4 val = *(f32x4*)(Cf + row * BNT + c4 * 4);
                const long grow = bm * 128 + h * 64 + row;
                if (bn * BNT < OUT_D)
                    *(f32x4*)(outF + grow * OUT_D + bn * BNT + c4 * 4) = val;
                else
                    *(f32x4*)(outF + (long)B_ROWS * OUT_D + grow * O2C_D
                              + (bn * BNT - OUT_D) + c4 * 4) = val;
            }
        }
    }
}

// ---------------- L3 deep-pipelined GEMM: 256x128, tri-buffer (R4 schedule) ----------------
// 8 waves (4M x 2N), per-wave 64x64. BK=64, 2 phases/K-tile. Requires K >= 128.
// SCHEDULE = round-4 version (57us proven). R5's fragment ping-pong with counted
// lgkmcnt REGRESSED to 95us (compiler inserts conservative waits around asm
// waitcnt + sched_barrier; m131-m141 plateau) — do not reintroduce.
// Tri-buffer: tile t read from buf[t%3]; stage targets buf[(t+2)%3] (3 loads/phase).
// vmcnt(6) once per K-tile: tile t+1's 6 loads drain while t+2's stay in flight.
// GRID = round-5 remap (FETCH 133->33MB proven): linear 256; xcd=i&7,
// bm=(i&7)+8*((i>>3)&3), bn=i>>5 -> the 8 blocks sharing an A-tile (same bm)
// land on ONE XCD (dispatch round-robins i%8) -> A fetched from HBM once.
// Output: bias+tanh -> bf16 hB + fp32 h.
__launch_bounds__(512, 1)
__global__ void gemm256(const unsigned short* __restrict__ A,
                        const unsigned short* __restrict__ Bt,
                        int K, const float* __restrict__ bias,
                        unsigned short* __restrict__ outB,
                        float* __restrict__ outF) {
    constexpr int ABUF = 256 * 64;           // ushorts (32 KB)
    constexpr int BBUF = 128 * 64;           // ushorts (16 KB)
    constexpr int BUFE = ABUF + BBUF;        // 48 KB
    __shared__ alignas(16) unsigned short smem[3 * BUFE];   // 144 KB

    const int tid  = threadIdx.x;
    const int wave = tid >> 6;
    const int lane = tid & 63;
    const int i  = blockIdx.x;
    const int bm = (i & 7) + 8 * ((i >> 3) & 3);   // same-bm octet -> same XCD
    const int bn = i >> 5;
    const int wm = wave >> 1, wn = wave & 1;
    const int lr = lane >> 4;
    const int lc = lane & 15;
    const int sw = lc & 7;
    const int nt = K >> 6;

    f32x4 acc[4][4] = {};

    long aoff[4], boff[2];
    #pragma unroll
    for (int j = 0; j < 4; ++j) {
        const int c   = tid + j * 512;
        const int row = c >> 3;
        const int kg  = (c & 7) ^ (row & 7);
        aoff[j] = (long)(bm * 256 + row) * K + kg * 8;
    }
    #pragma unroll
    for (int j = 0; j < 2; ++j) {
        const int c   = tid + j * 512;
        const int row = c >> 3;
        const int kg  = (c & 7) ^ (row & 7);
        boff[j] = (long)(bn * 128 + row) * K + kg * 8;
    }

    auto stageA2 = [&](int buf, int k0, int jlo) {   // 2 A loads
        char* base = (char*)(smem + buf * BUFE);
        load_lds16(A + aoff[jlo]     + k0, base + jlo       * 8192 + wave * 1024);
        load_lds16(A + aoff[jlo + 1] + k0, base + (jlo + 1) * 8192 + wave * 1024);
    };
    auto stageB1 = [&](int buf, int k0, int j) {     // 1 B load
        char* base = (char*)(smem + buf * BUFE) + ABUF * 2;
        load_lds16(Bt + boff[j] + k0, base + j * 8192 + wave * 1024);
    };
    auto dsA = [&](int buf, int kh, bf16x8* af) {
        const unsigned short* sA = smem + buf * BUFE;
        const int ch = (kh * 4 + lr) ^ sw;
        #pragma unroll
        for (int m = 0; m < 4; ++m)
            af[m] = *(const bf16x8*)(sA + (wm * 64 + m * 16 + lc) * 64 + ch * 8);
    };
    auto dsB = [&](int buf, int kh, bf16x8* bf) {
        const unsigned short* sB = smem + buf * BUFE + ABUF;
        const int ch = (kh * 4 + lr) ^ sw;
        #pragma unroll
        for (int n = 0; n < 4; ++n)
            bf[n] = *(const bf16x8*)(sB + (wn * 64 + n * 16 + lc) * 64 + ch * 8);
    };

    // prologue: stage tiles 0 and 1
    stageA2(0, 0, 0); stageA2(0, 0, 2); stageB1(0, 0, 0); stageB1(0, 0, 1);
    if (nt > 1) {
        stageA2(1, 64, 0); stageA2(1, 64, 2); stageB1(1, 64, 0); stageB1(1, 64, 1);
        asm volatile("s_waitcnt vmcnt(6)" ::: "memory");   // tile 0 landed
    } else {
        asm volatile("s_waitcnt vmcnt(0)" ::: "memory");
    }
    __builtin_amdgcn_s_barrier();

    int cur = 0;
    for (int t = 0; t < nt; ++t) {
        const int  k2   = (t + 2) << 6;
        const bool st   = (t + 2) < nt;
        const int  nbuf = (cur >= 1) ? cur - 1 : cur + 2;   // (t+2)%3

        bf16x8 af[4], bf[4];

        // ---- phase 0 (kh=0) ----
        if (st) { stageA2(nbuf, k2, 0); stageB1(nbuf, k2, 0); }
        dsA(cur, 0, af); dsB(cur, 0, bf);
        __builtin_amdgcn_s_barrier();
        asm volatile("s_waitcnt lgkmcnt(0)" ::: "memory");
        __builtin_amdgcn_sched_barrier(0);
        __builtin_amdgcn_s_setprio(1);
        #pragma unroll
        for (int m = 0; m < 4; ++m)
            #pragma unroll
            for (int n = 0; n < 4; ++n)
                acc[m][n] = __builtin_amdgcn_mfma_f32_16x16x32_bf16(af[m], bf[n], acc[m][n], 0, 0, 0);
        __builtin_amdgcn_s_setprio(0);
        __builtin_amdgcn_s_barrier();

        // ---- phase 1 (kh=1) ----
        if (st) { stageA2(nbuf, k2, 2); stageB1(nbuf, k2, 1); }
        dsA(cur, 1, af); dsB(cur, 1, bf);
        if (t + 1 < nt) {
            if (st) asm volatile("s_waitcnt vmcnt(6)" ::: "memory");  // tile t+1 landed
            else    asm volatile("s_waitcnt vmcnt(0)" ::: "memory");  // tail drain
        }
        __builtin_amdgcn_s_barrier();
        asm volatile("s_waitcnt lgkmcnt(0)" ::: "memory");
        __builtin_amdgcn_sched_barrier(0);
        __builtin_amdgcn_s_setprio(1);
        #pragma unroll
        for (int m = 0; m < 4; ++m)
            #pragma unroll
            for (int n = 0; n < 4; ++n)
                acc[m][n] = __builtin_amdgcn_mfma_f32_16x16x32_bf16(af[m], bf[n], acc[m][n], 0, 0, 0);
        __builtin_amdgcn_s_setprio(0);
        __builtin_amdgcn_s_barrier();

        cur = (cur == 2) ? 0 : cur + 1;
    }

    // ---- epilogue: bias + tanh, then staged coalesced writes ----
    #pragma unroll
    for (int n = 0; n < 4; ++n) {
        const float bv = bias[bn * 128 + wn * 64 + n * 16 + lc];
        #pragma unroll
        for (int m = 0; m < 4; ++m)
            #pragma unroll
            for (int r = 0; r < 4; ++r)
                acc[m][n][r] = tanhf(acc[m][n][r] + bv);
    }

    // bf16 tile (256x128 = 64 KB)
    unsigned short* Cb = smem;
    __syncthreads();
    #pragma unroll
    for (int m = 0; m < 4; ++m)
        #pragma unroll
        for (int n = 0; n < 4; ++n)
            #pragma unroll
            for (int r = 0; r < 4; ++r)
                Cb[(wm * 64 + m * 16 + lr * 4 + r) * 128 + wn * 64 + n * 16 + lc] =
                    f2bf(acc[m][n][r]);
    __syncthreads();
    #pragma unroll
    for (int tch = 0; tch < 8; ++tch) {
        const int chunk = tch * 512 + tid;
        const int row = chunk >> 4;       // 16 chunks of 16B per row
        const int c8  = chunk & 15;
        ushort8 v = *(ushort8*)(Cb + row * 128 + c8 * 8);
        *(ushort8*)(outB + (long)(bm * 256 + row) * RNN_D + bn * 128 + c8 * 8) = v;
    }
    __syncthreads();

    // fp32 tile (256x128 = 128 KB)
    float* Cf = (float*)smem;
    #pragma unroll
    for (int m = 0; m < 4; ++m)
        #pragma unroll
        for (int n = 0; n < 4; ++n)
            #pragma unroll
            for (int r = 0; r < 4; ++r)
                Cf[(wm * 64 + m * 16 + lr * 4 + r) * 128 + wn * 64 + n * 16 + lc] =
                    acc[m][n][r];
    __syncthreads();
    #pragma unroll
    for (int tch = 0; tch < 16; ++tch) {
        const int chunk = tch * 512 + tid;
        const int row = chunk >> 5;       // 32 f32x4 per row
        const int c4  = chunk & 31;
        f32x4 v = *(f32x4*)(Cf + row * 128 + c4 * 4);
        *(f32x4*)(outF + (long)(bm * 256 + row) * RNN_D + bn * 128 + c4 * 4) = v;
    }
}

// ---------------- launch ----------------
extern "C" void kernel_launch(void* const* d_in, const int* in_sizes, int n_in,
                              void* d_out, int out_size, void* d_ws, size_t ws_size,
                              hipStream_t stream) {
    const float* inputs = (const float*)d_in[0];
    const float* center = (const float*)d_in[1];
    const float* mstate = (const float*)d_in[2];
    const float* W_read = (const float*)d_in[3];
    const float* W_pre  = (const float*)d_in[4];
    const float* b_pre  = (const float*)d_in[5];
    const float* Wx     = (const float*)d_in[6];
    const float* Wh     = (const float*)d_in[7];
    const float* b_rnn  = (const float*)d_in[8];
    const float* W_post = (const float*)d_in[9];
    const float* b_post = (const float*)d_in[10];
    float* out = (float*)d_out;

    char* ws = (char*)d_ws;
    float* partials = (float*)ws;                                  // 128 floats
    unsigned short* WreadT = (unsigned short*)(ws + 1024);         // 256 x 512
    unsigned short* WpreT  = WreadT + 256 * 512;                   // 1024 x 768
    unsigned short* WxhT   = WpreT  + 1024 * 768;                  // 1024 x 2048
    unsigned short* WpostT = WxhT   + (long)1024 * 2048;           // 768 x 1024
    unsigned short* csB    = WpostT + 768 * 1024;                  // 8192 x 512
    unsigned short* miB    = csB + (long)B_ROWS * 512;             // 8192 x 768  [inputs | ctx]
    unsigned short* rnB    = miB + (long)B_ROWS * MIN_D;           // 8192 x 2048 [rnn_in | ms]
    unsigned short* hB     = rnB + (long)B_ROWS * 2048;            // 8192 x 1024

    prep_all<<<10176, 256, 0, stream>>>(W_read, partials,
                                        W_pre, Wx, Wh, W_post,
                                        WpreT, WxhT, WpostT, WreadT,
                                        center, inputs, mstate, csB, miB, rnB);

    // L1: context = (cs @ W_read) * clipscale -> miB cols [512..767]
    gemm_bt<0, 64><<<dim3(64, 4), 256, 0, stream>>>(csB, WreadT, 512, partials,
                                                    miB + 512, MIN_D, nullptr, 0);
    // L2: rnn_in = relu(mi @ W_pre + b_pre) -> rnB cols [0..1023]
    //     BNT=64, 1024 blocks = 4/CU (537 TF regime; BNT=128@2/CU was ~347 TF)
    gemm_bt<1, 64><<<dim3(64, 16), 256, 0, stream>>>(miB, WpreT, 768, b_pre,
                                                     rnB, 2048, nullptr, 0);
    // L3: h = tanh([rnn_in|ms] @ [Wx;Wh] + b_rnn) -> hB (bf16) + d_out region 2 (fp32)
    gemm256<<<256, 512, 0, stream>>>(rnB, WxhT, 2048, b_rnn,
                                     hB, out + (long)B_ROWS * TOT_D);
    // L4: module_output = relu(h @ W_post + b_post) -> fp32 d_out regions 0/1
    gemm_bt<3, 64><<<dim3(64, 12), 256, 0, stream>>>(hB, WpostT, 1024, b_post,
                                                     nullptr, 0, out, 0);
}